// Round 7
// baseline (5719.848 us; speedup 1.0000x reference)
//
#include <hip/hip_runtime.h>
#include <math.h>

#define WW 256
#define HH 256
#define DDP 96
#define HWP (WW*HH)
#define DHW (DDP*HWP)
#define N2 (2*DHW)
#define N4 (4*DHW)
#define TX 64
#define TY 16
#define NT 512
#define ZS 16
#define NSLAB (DDP/ZS)          // 6
#define GXB (WW/TX)             // 4
#define GYB (HH/TY)             // 16
#define NBLK (GXB*GYB*4*NSLAB)  // 1536
#define RED_BLOCKS 1024

typedef unsigned int u32;
typedef unsigned short u16;

__device__ __forceinline__ float fmin3(float a,float b,float c){return fminf(a,fminf(b,c));}
__device__ __forceinline__ float fmax3(float a,float b,float c){return fmaxf(a,fmaxf(b,c));}
__device__ __forceinline__ float sigm(float x){return 1.f/(1.f+expf(-x));}
__device__ __forceinline__ int   icl(int v,int hi){return min(max(v,0),hi);}
__device__ __forceinline__ float bf2f(u16 h){u32 u=((u32)h)<<16;return __builtin_bit_cast(float,u);}
__device__ __forceinline__ u16   f2bf(float f){u32 u=__builtin_bit_cast(u32,f);return (u16)((u+0x7fffu+((u>>16)&1u))>>16);}
__device__ __forceinline__ u32   pack2(float a,float b){return (u32)f2bf(a)|((u32)f2bf(b)<<16);}

// Fused 2-iteration skeletonization step. Reads g = e_t (halo +-3, one buffer),
// recomputes h = e_{t+1} = E(g), M(h), k = e_{t+2} = E(h), M(k) in LDS, applies two
// skel updates, writes k and skel. All pooling windows clamp coordinates at every
// level (== reference SAME padding); phantom-coordinate plane slots are never read.
// MODE: 0=FIRST (init-assign + u1, fp32 src w/ sigmoid for vols 0,1),
//       1=MID (2 compound updates), 2=LAST (1 compound update, no k write)
template<int MODE>
__global__ __launch_bounds__(NT) void skel_kernel(const u16* __restrict__ gsrc,
                                                  const float* __restrict__ ypred,
                                                  const float* __restrict__ ytrue,
                                                  u16* __restrict__ kdst,
                                                  u16* __restrict__ skel) {
    // XCD-aware bijective swizzle (NBLK % 8 == 0): neighbors share halo in L2
    int swz = (blockIdx.x & 7) * (NBLK/8) + (blockIdx.x >> 3);
    const int bx = swz % GXB;
    int rem = swz / GXB;
    const int by = rem % GYB;
    const int bz = rem / GYB;
    const int vol = bz / NSLAB;
    const int z0 = (bz % NSLAB) * ZS;
    const int x0 = bx*TX, y0 = by*TY;
    const size_t base = (size_t)vol*DHW;

    const int tx2 = threadIdx.x & 31;
    const int ty  = threadIdx.x >> 5;
    const int gxc = x0 + 2*tx2;
    const int gyc = y0 + ty;

    const float* fin = nullptr; bool dosig=false;
    if (MODE==0) { if (vol<2){fin=ypred+base;dosig=true;} else fin=ytrue+(size_t)(vol-2)*DHW; }

    // col convention for ALL planes: col c <-> px x0-4+c
    __shared__ float raw[22][72];      // g plane,   rows gy = y0-3+r (clamped at stage)
    __shared__ float P [3][20][72];    // E_xy(g),   rows gy = y0-2+j, cols [2,70)
    __shared__ float T1[20][72];       // h plane,   same extent as P
    __shared__ float Q [3][18][72];    // E_xy(h),   rows gy = y0-1+j, cols [3,69)
    __shared__ float T2[18][72];       // k plane,   same extent as Q

    float2 g0={0,0},g1={0,0},g2={0,0};       // g centers ring (z-3..z)
    float2 hc0={0,0},hc1={0,0},hc2={0,0};    // h centers ring
    float2 R0={0,0},R1={0,0},R2={0,0};       // M_xy(h) centers ring
    float2 S0={0,0},S1={0,0},S2={0,0};       // M_xy(k) centers ring
    float2 dt0={0,0},dt1={0,0};              // delta_t ring

    const int cl  = icl(gxc-1,WW-1)-(x0-4);
    const int cr  = icl(gxc+2,WW-1)-(x0-4);
    const int cm0 = 2*tx2+4, cm1 = 2*tx2+5;

    const int ziEnd = z0+ZS + (MODE==2 ? 1 : 2);
    for (int zi = z0-3; zi <= ziEnd; ++zi) {
        // ---------- stage 1: stage raw(zi) ----------
        if ((unsigned)zi < DDP) {
            if (MODE==0) {
                const float* pl = fin + (size_t)zi*HWP;
                for (int r = ty; r < 22; r += TY) {
                    const float* rp = pl + (size_t)icl(y0-3+r,HH-1)*WW;
                    for (int w = tx2; w < 36; w += 32) {
                        int gx0 = x0-4+2*w;
                        float v0,v1;
                        if (gx0 < 0)        { v0=v1=rp[0]; }
                        else if (gx0 >= WW) { v0=v1=rp[WW-1]; }
                        else { float2 fv = *(const float2*)(rp+gx0); v0=fv.x; v1=fv.y; }
                        if (dosig){v0=sigm(v0);v1=sigm(v1);}
                        *(float2*)&raw[r][2*w] = make_float2(v0,v1);
                    }
                }
            } else {
                const u16* pl = gsrc + base + (size_t)zi*HWP;
                for (int r = ty; r < 22; r += TY) {
                    const u16* rp = pl + (size_t)icl(y0-3+r,HH-1)*WW;
                    for (int w = tx2; w < 36; w += 32) {
                        int gx0 = x0-4+2*w;
                        float v0,v1;
                        if (gx0 < 0)        { v0=v1=bf2f(rp[0]); }
                        else if (gx0 >= WW) { v0=v1=bf2f(rp[WW-1]); }
                        else { u32 p = *(const u32*)(rp+gx0); v0=bf2f((u16)p); v1=bf2f((u16)(p>>16)); }
                        *(float2*)&raw[r][2*w] = make_float2(v0,v1);
                    }
                }
            }
        }
        __syncthreads();                                     // (1)
        // ---------- stage 2: P[zi] = E_xy(g), g-center ring ----------
        g0=g1; g1=g2;
        if ((unsigned)zi < DDP) {
            g2 = *(float2*)&raw[ty+3][2*tx2+4];
            float (*Pp)[72] = P[zi%3];
            for (int j = ty; j < 20; j += TY) {
                int gy = y0-2+j;
                int ra = icl(gy-1,HH-1)-(y0-3);
                int rb = icl(gy  ,HH-1)-(y0-3);
                int rc = icl(gy+1,HH-1)-(y0-3);
                for (int ii = tx2; ii < 68; ii += 32) {
                    int i = 2+ii;
                    int gx = x0-4+i;
                    int ca = icl(gx-1,WW-1)-(x0-4);
                    int cb = icl(gx  ,WW-1)-(x0-4);
                    int cc = icl(gx+1,WW-1)-(x0-4);
                    Pp[j][i] = fmin3( fmin3(raw[ra][ca],raw[ra][cb],raw[ra][cc]),
                                      fmin3(raw[rb][ca],raw[rb][cb],raw[rb][cc]),
                                      fmin3(raw[rc][ca],raw[rc][cb],raw[rc][cc]) );
                }
            }
        }
        __syncthreads();                                     // (2)
        // ---------- stage 3: T1 = h(zh) = min_z(P ring, clamped) ----------
        const int zh = zi-1;
        const bool doh = (zh>=0 && zh<DDP && zh<=z0+ZS+1);
        if (doh) {
            int sa = icl(zh-1,DDP-1)%3, sb = zh%3, sc = icl(zh+1,DDP-1)%3;
            for (int j = ty; j < 20; j += TY)
                for (int ii = tx2; ii < 68; ii += 32) {
                    int i = 2+ii;
                    T1[j][i] = fmin3(P[sa][j][i],P[sb][j][i],P[sc][j][i]);
                }
        }
        __syncthreads();                                     // (3)
        // ---------- stage 4: h centers, R = M_xy(h), Q = E_xy(h) ----------
        hc0=hc1; hc1=hc2; R0=R1; R1=R2;
        if (doh) {
            hc2 = *(float2*)&T1[ty+2][2*tx2+4];
            int ra = icl(gyc-1,HH-1)-(y0-2), rb = ty+2, rc = icl(gyc+1,HH-1)-(y0-2);
            float p0=-INFINITY, p1=-INFINITY;
            { float a=T1[ra][cl],b=T1[ra][cm0],c=T1[ra][cm1],d=T1[ra][cr];
              p0=fmaxf(p0,fmax3(a,b,c)); p1=fmaxf(p1,fmax3(b,c,d)); }
            { float a=T1[rb][cl],b=T1[rb][cm0],c=T1[rb][cm1],d=T1[rb][cr];
              p0=fmaxf(p0,fmax3(a,b,c)); p1=fmaxf(p1,fmax3(b,c,d)); }
            { float a=T1[rc][cl],b=T1[rc][cm0],c=T1[rc][cm1],d=T1[rc][cr];
              p0=fmaxf(p0,fmax3(a,b,c)); p1=fmaxf(p1,fmax3(b,c,d)); }
            R2 = make_float2(p0,p1);
            if (MODE != 2) {
                float (*Qp)[72] = Q[zh%3];
                for (int j = ty; j < 18; j += TY) {
                    int gy = y0-1+j;
                    int qa = icl(gy-1,HH-1)-(y0-2);
                    int qb = icl(gy  ,HH-1)-(y0-2);
                    int qc = icl(gy+1,HH-1)-(y0-2);
                    for (int ii = tx2; ii < 66; ii += 32) {
                        int i = 3+ii;
                        int gx = x0-4+i;
                        int ca = icl(gx-1,WW-1)-(x0-4);
                        int cb = icl(gx  ,WW-1)-(x0-4);
                        int cc = icl(gx+1,WW-1)-(x0-4);
                        Qp[j][i] = fmin3( fmin3(T1[qa][ca],T1[qa][cb],T1[qa][cc]),
                                          fmin3(T1[qb][ca],T1[qb][cb],T1[qb][cc]),
                                          fmin3(T1[qc][ca],T1[qc][cb],T1[qc][cc]) );
                    }
                }
            }
        }
        __syncthreads();                                     // (4)
        // ---------- stage 5: zk: T2 = k = min_z(Q), M1 = max_z(R), dt ----------
        const int zk = zi-2;
        const bool dok = (zk>=0 && zk>=z0-1 && zk<DDP && zk<=z0+ZS);
        dt0 = dt1;
        if (dok) {
            float M1x, M1y;
            if (zk==0)          { M1x=fmaxf(R1.x,R2.x); M1y=fmaxf(R1.y,R2.y); }
            else if (zk==DDP-1) { M1x=fmaxf(R0.x,R1.x); M1y=fmaxf(R0.y,R1.y); }
            else                { M1x=fmax3(R0.x,R1.x,R2.x); M1y=fmax3(R0.y,R1.y,R2.y); }
            dt1 = make_float2(fmaxf(g0.x-M1x,0.f), fmaxf(g0.y-M1y,0.f));
            if (MODE==2) {
                if (zk>=z0 && zk<z0+ZS) {
                    size_t idx = base + (size_t)zk*HWP + (size_t)gyc*WW + gxc;
                    u32 sp = *(const u32*)(skel+idx);
                    float s0=bf2f((u16)sp), s1=bf2f((u16)(sp>>16));
                    s0 += fmaxf(dt1.x - s0*dt1.x, 0.f);
                    s1 += fmaxf(dt1.y - s1*dt1.y, 0.f);
                    *(u32*)(skel+idx) = pack2(s0,s1);
                }
            } else {
                int sa = icl(zk-1,DDP-1)%3, sb = zk%3, sc = icl(zk+1,DDP-1)%3;
                for (int j = ty; j < 18; j += TY)
                    for (int ii = tx2; ii < 66; ii += 32) {
                        int i = 3+ii;
                        T2[j][i] = fmin3(Q[sa][j][i],Q[sb][j][i],Q[sc][j][i]);
                    }
            }
        }
        __syncthreads();                                     // (5)
        // ---------- stage 6: S = M_xy(k), k write, M2 = max_z(S), skel ----------
        if (MODE != 2) {
            S0=S1; S1=S2;
            if (dok) {
                int ua = icl(gyc-1,HH-1)-(y0-1), ub = ty+1, uc = icl(gyc+1,HH-1)-(y0-1);
                float p0=-INFINITY, p1=-INFINITY;
                { float a=T2[ua][cl],b=T2[ua][cm0],c=T2[ua][cm1],d=T2[ua][cr];
                  p0=fmaxf(p0,fmax3(a,b,c)); p1=fmaxf(p1,fmax3(b,c,d)); }
                { float a=T2[ub][cl],b=T2[ub][cm0],c=T2[ub][cm1],d=T2[ub][cr];
                  p0=fmaxf(p0,fmax3(a,b,c)); p1=fmaxf(p1,fmax3(b,c,d)); }
                { float a=T2[uc][cl],b=T2[uc][cm0],c=T2[uc][cm1],d=T2[uc][cr];
                  p0=fmaxf(p0,fmax3(a,b,c)); p1=fmaxf(p1,fmax3(b,c,d)); }
                S2 = make_float2(p0,p1);
                if (zk>=z0 && zk<z0+ZS) {
                    float2 kc = *(float2*)&T2[ty+1][2*tx2+4];
                    *(u32*)(kdst + base + (size_t)zk*HWP + (size_t)gyc*WW + gxc) = pack2(kc.x,kc.y);
                }
            }
            const int zm = zi-3;
            if (zm>=z0 && zm<z0+ZS) {
                float M2x, M2y;
                if (zm==0)          { M2x=fmaxf(S1.x,S2.x); M2y=fmaxf(S1.y,S2.y); }
                else if (zm==DDP-1) { M2x=fmaxf(S0.x,S1.x); M2y=fmaxf(S0.y,S1.y); }
                else                { M2x=fmax3(S0.x,S1.x,S2.x); M2y=fmax3(S0.y,S1.y,S2.y); }
                float d2x = fmaxf(hc0.x-M2x,0.f), d2y = fmaxf(hc0.y-M2y,0.f);
                size_t idx = base + (size_t)zm*HWP + (size_t)gyc*WW + gxc;
                float s0, s1;
                if (MODE==0) { s0=dt0.x; s1=dt0.y; }
                else {
                    u32 sp = *(const u32*)(skel+idx);
                    s0=bf2f((u16)sp); s1=bf2f((u16)(sp>>16));
                    s0 += fmaxf(dt0.x - s0*dt0.x, 0.f);
                    s1 += fmaxf(dt0.y - s1*dt0.y, 0.f);
                }
                s0 += fmaxf(d2x - s0*d2x, 0.f);
                s1 += fmaxf(d2y - s1*d2y, 0.f);
                *(u32*)(skel+idx) = pack2(s0,s1);
            }
        }
    }
}

// ---------------- deterministic 4-sum reduction (vols 0,1 = pred; 2,3 = true) ----------------
__global__ __launch_bounds__(256) void reduce4_kernel(const u16* __restrict__ skel,
                                                      const float* __restrict__ ytrue,
                                                      const float* __restrict__ ypred,
                                                      float* __restrict__ part) {
    const u32* sp = (const u32*)skel;
    const u32* st = (const u32*)(skel + N2);
    const float2* yt = (const float2*)ytrue;
    const float2* yp = (const float2*)ypred;
    float a0=0.f,a1=0.f,a2=0.f,a3=0.f;
    for (int i = blockIdx.x*256 + threadIdx.x; i < N2/2; i += gridDim.x*256) {
        u32 a = sp[i]; u32 b = st[i];
        float2 t = yt[i]; float2 q = yp[i];
        float s0=bf2f((u16)a), s1=bf2f((u16)(a>>16));
        float u0=bf2f((u16)b), u1=bf2f((u16)(b>>16));
        a0 += s0*t.x + s1*t.y;
        a1 += s0 + s1;
        a2 += u0*sigm(q.x) + u1*sigm(q.y);
        a3 += u0 + u1;
    }
    for (int off=32; off>0; off>>=1) {
        a0+=__shfl_down(a0,off); a1+=__shfl_down(a1,off);
        a2+=__shfl_down(a2,off); a3+=__shfl_down(a3,off);
    }
    __shared__ float red[4][4];
    int wave = threadIdx.x>>6;
    if ((threadIdx.x&63)==0){red[wave][0]=a0;red[wave][1]=a1;red[wave][2]=a2;red[wave][3]=a3;}
    __syncthreads();
    if (threadIdx.x==0){
        float s0=0,s1=0,s2=0,s3=0;
        for(int w=0;w<4;++w){s0+=red[w][0];s1+=red[w][1];s2+=red[w][2];s3+=red[w][3];}
        part[0*RED_BLOCKS+blockIdx.x]=s0; part[1*RED_BLOCKS+blockIdx.x]=s1;
        part[2*RED_BLOCKS+blockIdx.x]=s2; part[3*RED_BLOCKS+blockIdx.x]=s3;
    }
}

__global__ __launch_bounds__(256) void finalize_kernel(const float* __restrict__ part,
                                                       float* __restrict__ out) {
    float a0=0.f,a1=0.f,a2=0.f,a3=0.f;
    for (int i=threadIdx.x;i<RED_BLOCKS;i+=256){
        a0+=part[0*RED_BLOCKS+i]; a1+=part[1*RED_BLOCKS+i];
        a2+=part[2*RED_BLOCKS+i]; a3+=part[3*RED_BLOCKS+i];
    }
    for (int off=32; off>0; off>>=1){
        a0+=__shfl_down(a0,off); a1+=__shfl_down(a1,off);
        a2+=__shfl_down(a2,off); a3+=__shfl_down(a3,off);
    }
    __shared__ float red[4][4];
    int wave = threadIdx.x>>6;
    if ((threadIdx.x&63)==0){red[wave][0]=a0;red[wave][1]=a1;red[wave][2]=a2;red[wave][3]=a3;}
    __syncthreads();
    if (threadIdx.x==0){
        float s0=0,s1=0,s2=0,s3=0;
        for(int w=0;w<4;++w){s0+=red[w][0];s1+=red[w][1];s2+=red[w][2];s3+=red[w][3];}
        float tprec=(s0+1.f)/(s1+1.f);
        float tsens=(s2+1.f)/(s3+1.f);
        float cl2=2.f*tprec*tsens/(tprec+tsens+1.f);
        out[0]=1.f-cl2;
    }
}

__global__ void sentinel_kernel(float* out, float v){ out[0]=v; }

extern "C" void kernel_launch(void* const* d_in, const int* in_sizes, int n_in,
                              void* d_out, int out_size, void* d_ws, size_t ws_size,
                              hipStream_t stream) {
    const float* ypred = (const float*)d_in[0];
    const float* ytrue = (const float*)d_in[1];
    float* out = (float*)d_out;

    const size_t need = (size_t)3*N4*sizeof(u16) + (size_t)4*RED_BLOCKS*sizeof(float);
    if (ws_size < need) { sentinel_kernel<<<1,1,0,stream>>>(out,-111111.f); return; }

    u16* EA   = (u16*)d_ws;
    u16* EB   = EA + N4;
    u16* SKEL = EB + N4;
    float* PART = (float*)(SKEL + N4);

    // FIRST: init-assign + update1; writes e_2 -> EA
    skel_kernel<0><<<NBLK, NT, 0, stream>>>(EA, ypred, ytrue, EA, SKEL);
    // 19 MID kernels: updates u2..u39, each reads e_{2i}, writes e_{2i+2}
    u16* cur = EA; u16* oth = EB;
    for (int i = 0; i < 19; ++i) {
        skel_kernel<1><<<NBLK, NT, 0, stream>>>(cur, nullptr, nullptr, oth, SKEL);
        u16* t = cur; cur = oth; oth = t;
    }
    // LAST: update u40 (reads e_40, recomputes e_41 internally, no k write)
    skel_kernel<2><<<NBLK, NT, 0, stream>>>(cur, nullptr, nullptr, oth, SKEL);

    reduce4_kernel<<<RED_BLOCKS, 256, 0, stream>>>(SKEL, ytrue, ypred, PART);
    finalize_kernel<<<1, 256, 0, stream>>>(PART, out);
}

// Round 8
// 2772.282 us; speedup vs baseline: 2.0632x; 2.0632x over previous
//
#include <hip/hip_runtime.h>
#include <math.h>

#define WW 256
#define HH 256
#define DDP 96
#define HWP (WW*HH)
#define DHW (DDP*HWP)
#define N2 (2*DHW)
#define N4 (4*DHW)
#define TX 64                   // 32 lanes x 2 px
#define TY 8
#define NT 256
#define ZS 12
#define NSLAB (DDP/ZS)          // 8
#define RED_BLOCKS 1024
#define NITER 40
#define RCOLS 68                // raw cols: px x0-2 .. x0+65
#define RPAIRS 34

typedef unsigned int u32;
typedef unsigned short u16;

__device__ __forceinline__ float fmin3(float a,float b,float c){return fminf(a,fminf(b,c));}
__device__ __forceinline__ float fmax3(float a,float b,float c){return fmaxf(a,fmaxf(b,c));}
__device__ __forceinline__ float sigm(float x){return 1.f/(1.f+expf(-x));}
__device__ __forceinline__ int   icl(int v,int hi){return min(max(v,0),hi);}
__device__ __forceinline__ float bf2f(u16 h){u32 u=((u32)h)<<16;return __builtin_bit_cast(float,u);}
__device__ __forceinline__ u16   f2bf(float f){u32 u=__builtin_bit_cast(u32,f);return (u16)((u+0x7fffu+((u>>16)&1u))>>16);}
__device__ __forceinline__ u32   pack2(float a,float b){return (u32)f2bf(a)|((u32)f2bf(b)<<16);}

// MODE 0: init erode  — stage fp32 input, write e1 = E(f(x)) (sigmoid-at-write for vols 0,1)
// MODE 1: fused first — ghalo=e1, aimg from fp32 input (sigmoided), skel init; write e2
// MODE 2: fused mid   — skel RMW update; eaw read pointwise then overwritten with e_{t+2}
// MODE 3: fused last  — skel RMW update only, no e write
template<int MODE>
__global__ __launch_bounds__(NT) void step_kernel(const u16* __restrict__ ghalo,
                                                  u16* __restrict__ eaw,
                                                  const float* __restrict__ ypred,
                                                  const float* __restrict__ ytrue,
                                                  u16* __restrict__ skel) {
    const int tx2 = threadIdx.x & 31;
    const int ty  = threadIdx.x >> 5;
    const int x0 = blockIdx.x * TX;
    const int y0 = blockIdx.y * TY;
    const int vol = blockIdx.z / NSLAB;
    const int z0 = (blockIdx.z % NSLAB) * ZS;
    const size_t base = (size_t)vol * DHW;
    const int gxc = x0 + 2*tx2;
    const int gyc = y0 + ty;

    const float* fin = nullptr;
    bool dosig = false;
    if (MODE == 0 || MODE == 1) {
        if (vol < 2) { fin = ypred + base; dosig = true; }
        else         { fin = ytrue + (size_t)(vol-2)*DHW; }
    }

    // raw rows r: gy = y0-1+r (stage-clamped); col c: px = x0-2+c (stage-clamped).
    __shared__ __align__(16) float raw[2][TY+2][RCOLS];

    auto stage = [&](int zi, int buf) {
        if ((unsigned)zi >= DDP) return;
        if (MODE == 0) {
            const float* pl = fin + (size_t)zi * HWP;
            for (int idx = threadIdx.x; idx < (TY+2)*RPAIRS; idx += NT) {
                int r = idx / RPAIRS;
                int w = idx - r*RPAIRS;
                const float* rp = pl + (size_t)icl(y0-1+r, HH-1) * WW;
                int gx0 = x0 - 2 + 2*w;
                float v0, v1;
                if (gx0 < 0)        { v0 = v1 = rp[0]; }
                else if (gx0 >= WW) { v0 = v1 = rp[WW-1]; }
                else { float2 fv = *(const float2*)(rp + gx0); v0 = fv.x; v1 = fv.y; }
                *(float2*)&raw[buf][r][2*w] = make_float2(v0, v1);
            }
        } else {
            const u16* pl = ghalo + base + (size_t)zi * HWP;
            for (int idx = threadIdx.x; idx < (TY+2)*RPAIRS; idx += NT) {
                int r = idx / RPAIRS;
                int w = idx - r*RPAIRS;
                const u16* rp = pl + (size_t)icl(y0-1+r, HH-1) * WW;
                int gx0 = x0 - 2 + 2*w;
                float v0, v1;
                if (gx0 < 0)        { v0 = v1 = bf2f(rp[0]); }
                else if (gx0 >= WW) { v0 = v1 = bf2f(rp[WW-1]); }
                else { u32 p = *(const u32*)(rp + gx0); v0 = bf2f((u16)p); v1 = bf2f((u16)(p>>16)); }
                *(float2*)&raw[buf][r][2*w] = make_float2(v0, v1);
            }
        }
    };

    const int c0 = 2*tx2;     // left f2 read col; output px pair at cols c0+2, c0+3
    float2 nr0, nr1, nr2;     // E_xy z-ring
    float2 mr0, mr1, mr2;     // M_xy z-ring
    nr0 = nr1 = nr2 = make_float2(INFINITY, INFINITY);
    mr0 = mr1 = mr2 = make_float2(-INFINITY, -INFINITY);

    stage(z0-1, (z0-1)&1);
    __syncthreads();

    for (int zi = z0-1; zi <= z0+ZS; ++zi) {
        if (zi < z0+ZS) stage(zi+1, (zi+1)&1);    // issue next plane's loads early

        float2 axn = make_float2(INFINITY, INFINITY);
        float2 axm = make_float2(-INFINITY, -INFINITY);
        if ((unsigned)zi < DDP) {
            const int b = zi & 1;
            float2 La = *(const float2*)&raw[b][ty  ][c0];
            float2 Ma = *(const float2*)&raw[b][ty  ][c0+2];
            float2 Ra = *(const float2*)&raw[b][ty  ][c0+4];
            float2 Lb = *(const float2*)&raw[b][ty+1][c0];
            float2 Mb = *(const float2*)&raw[b][ty+1][c0+2];
            float2 Rb = *(const float2*)&raw[b][ty+1][c0+4];
            float2 Lc = *(const float2*)&raw[b][ty+2][c0];
            float2 Mc = *(const float2*)&raw[b][ty+2][c0+2];
            float2 Rc = *(const float2*)&raw[b][ty+2][c0+4];
            // min: per-row shared middle pair, then row fold
            float sa = fminf(Ma.x, Ma.y), sb = fminf(Mb.x, Mb.y), sc = fminf(Mc.x, Mc.y);
            axn.x = fmin3(fminf(sa, La.y), fminf(sb, Lb.y), fminf(sc, Lc.y));
            axn.y = fmin3(fminf(sa, Ra.x), fminf(sb, Rb.x), fminf(sc, Rc.x));
            if (MODE != 0) {
                float ta = fmaxf(Ma.x, Ma.y), tb = fmaxf(Mb.x, Mb.y), tc = fmaxf(Mc.x, Mc.y);
                axm.x = fmax3(fmaxf(ta, La.y), fmaxf(tb, Lb.y), fmaxf(tc, Lc.y));
                axm.y = fmax3(fmaxf(ta, Ra.x), fmaxf(tb, Rb.x), fmaxf(tc, Rc.x));
            }
        }
        nr0 = nr1; nr1 = nr2; nr2 = axn;
        if (MODE != 0) { mr0 = mr1; mr1 = mr2; mr2 = axm; }

        if (zi >= z0+1) {
            const int zc = zi - 1;
            size_t voff = (size_t)zc*HWP + (size_t)gyc*WW + gxc;
            size_t idx = base + voff;
            float e0 = fmin3(nr0.x, nr1.x, nr2.x);
            float e1 = fmin3(nr0.y, nr1.y, nr2.y);
            if (MODE == 0) {
                if (dosig) { e0 = sigm(e0); e1 = sigm(e1); }
                *(u32*)(eaw + idx) = pack2(e0, e1);
            } else {
                float M3x = fmax3(mr0.x, mr1.x, mr2.x);
                float M3y = fmax3(mr0.y, mr1.y, mr2.y);
                float av0, av1;
                if (MODE == 1) {
                    float2 fv = *(const float2*)(fin + voff);
                    av0 = fv.x; av1 = fv.y;
                    if (dosig) { av0 = sigm(av0); av1 = sigm(av1); }
                } else {
                    u32 ap = *(const u32*)(eaw + idx);
                    av0 = bf2f((u16)ap); av1 = bf2f((u16)(ap>>16));
                }
                float d0 = fmaxf(av0 - M3x, 0.f);
                float d1 = fmaxf(av1 - M3y, 0.f);
                u32 pk;
                if (MODE == 1) {
                    pk = pack2(d0, d1);
                } else {
                    u32 sp = *(const u32*)(skel + idx);
                    float s0 = bf2f((u16)sp), s1 = bf2f((u16)(sp>>16));
                    s0 += fmaxf(d0 - s0*d0, 0.f);
                    s1 += fmaxf(d1 - s1*d1, 0.f);
                    pk = pack2(s0, s1);
                }
                *(u32*)(skel + idx) = pk;
                if (MODE != 3) *(u32*)(eaw + idx) = pack2(e0, e1);
            }
        }
        __syncthreads();
    }
}

// ---------------- deterministic 4-sum reduction (vols 0,1 = pred; 2,3 = true) ----------------
__global__ __launch_bounds__(256) void reduce4_kernel(const u16* __restrict__ skel,
                                                      const float* __restrict__ ytrue,
                                                      const float* __restrict__ ypred,
                                                      float* __restrict__ part) {
    const u32* sp = (const u32*)skel;
    const u32* st = (const u32*)(skel + N2);
    const float2* yt = (const float2*)ytrue;
    const float2* yp = (const float2*)ypred;
    float a0=0.f,a1=0.f,a2=0.f,a3=0.f;
    for (int i = blockIdx.x*256 + threadIdx.x; i < N2/2; i += gridDim.x*256) {
        u32 a = sp[i]; u32 b = st[i];
        float2 t = yt[i]; float2 q = yp[i];
        float s0=bf2f((u16)a), s1=bf2f((u16)(a>>16));
        float u0=bf2f((u16)b), u1=bf2f((u16)(b>>16));
        a0 += s0*t.x + s1*t.y;
        a1 += s0 + s1;
        a2 += u0*sigm(q.x) + u1*sigm(q.y);
        a3 += u0 + u1;
    }
    for (int off=32; off>0; off>>=1) {
        a0+=__shfl_down(a0,off); a1+=__shfl_down(a1,off);
        a2+=__shfl_down(a2,off); a3+=__shfl_down(a3,off);
    }
    __shared__ float red[4][4];
    int wave = threadIdx.x>>6;
    if ((threadIdx.x&63)==0){red[wave][0]=a0;red[wave][1]=a1;red[wave][2]=a2;red[wave][3]=a3;}
    __syncthreads();
    if (threadIdx.x==0){
        float s0=0,s1=0,s2=0,s3=0;
        for(int w=0;w<4;++w){s0+=red[w][0];s1+=red[w][1];s2+=red[w][2];s3+=red[w][3];}
        part[0*RED_BLOCKS+blockIdx.x]=s0; part[1*RED_BLOCKS+blockIdx.x]=s1;
        part[2*RED_BLOCKS+blockIdx.x]=s2; part[3*RED_BLOCKS+blockIdx.x]=s3;
    }
}

__global__ __launch_bounds__(256) void finalize_kernel(const float* __restrict__ part,
                                                       float* __restrict__ out) {
    float a0=0.f,a1=0.f,a2=0.f,a3=0.f;
    for (int i=threadIdx.x;i<RED_BLOCKS;i+=256){
        a0+=part[0*RED_BLOCKS+i]; a1+=part[1*RED_BLOCKS+i];
        a2+=part[2*RED_BLOCKS+i]; a3+=part[3*RED_BLOCKS+i];
    }
    for (int off=32; off>0; off>>=1){
        a0+=__shfl_down(a0,off); a1+=__shfl_down(a1,off);
        a2+=__shfl_down(a2,off); a3+=__shfl_down(a3,off);
    }
    __shared__ float red[4][4];
    int wave = threadIdx.x>>6;
    if ((threadIdx.x&63)==0){red[wave][0]=a0;red[wave][1]=a1;red[wave][2]=a2;red[wave][3]=a3;}
    __syncthreads();
    if (threadIdx.x==0){
        float s0=0,s1=0,s2=0,s3=0;
        for(int w=0;w<4;++w){s0+=red[w][0];s1+=red[w][1];s2+=red[w][2];s3+=red[w][3];}
        float tprec=(s0+1.f)/(s1+1.f);
        float tsens=(s2+1.f)/(s3+1.f);
        float cl2=2.f*tprec*tsens/(tprec+tsens+1.f);
        out[0]=1.f-cl2;
    }
}

__global__ void sentinel_kernel(float* out, float v){ out[0]=v; }

extern "C" void kernel_launch(void* const* d_in, const int* in_sizes, int n_in,
                              void* d_out, int out_size, void* d_ws, size_t ws_size,
                              hipStream_t stream) {
    const float* ypred = (const float*)d_in[0];
    const float* ytrue = (const float*)d_in[1];
    float* out = (float*)d_out;

    const size_t need = (size_t)3*N4*sizeof(u16) + (size_t)4*RED_BLOCKS*sizeof(float);
    if (ws_size < need) { sentinel_kernel<<<1,1,0,stream>>>(out,-111111.f); return; }

    u16* EA   = (u16*)d_ws;
    u16* EB   = EA + N4;
    u16* SKEL = EB + N4;
    float* PART = (float*)(SKEL + N4);

    dim3 grid(WW/TX, HH/TY, 4*NSLAB);   // 4 x 32 x 32 = 4096 blocks

    // EB = e_1 = E(f(x))   (sigmoid fused at write for pred vols)
    step_kernel<0><<<grid, NT, 0, stream>>>(nullptr, EB, ypred, ytrue, nullptr);
    // skel = relu(e_0 - M(e_1));  EA <- e_2 = E(e_1)
    step_kernel<1><<<grid, NT, 0, stream>>>(EB, EA, ypred, ytrue, SKEL);

    u16* h = EA;   // e_{t+1}
    u16* a = EB;   // e_t  (overwritten with e_{t+2})
    for (int t = 1; t <= NITER; ++t) {
        if (t < NITER) step_kernel<2><<<grid, NT, 0, stream>>>(h, a, nullptr, nullptr, SKEL);
        else           step_kernel<3><<<grid, NT, 0, stream>>>(h, a, nullptr, nullptr, SKEL);
        u16* tmp = h; h = a; a = tmp;
    }

    reduce4_kernel<<<RED_BLOCKS, 256, 0, stream>>>(SKEL, ytrue, ypred, PART);
    finalize_kernel<<<1, 256, 0, stream>>>(PART, out);
}

// Round 10
// 2405.448 us; speedup vs baseline: 2.3779x; 1.1525x over previous
//
#include <hip/hip_runtime.h>
#include <hip/hip_fp16.h>
#include <math.h>

#define WW 256
#define HH 256
#define DDP 96
#define HWP (WW*HH)
#define DHW (DDP*HWP)
#define N2 (2*DHW)
#define N4 (4*DHW)
#define TX 64                   // 32 lanes x 2 px
#define TY 8
#define NT 256
#define ZS 12
#define NSLAB (DDP/ZS)          // 8
#define RED_BLOCKS 1024
#define NITER 40
#define RPAIRS 34               // u32 pairs per row: px x0-2 .. x0+65

typedef unsigned int u32;
typedef unsigned short u16;
typedef __half2 h2;

__device__ __forceinline__ float sigm(float x){return 1.f/(1.f+expf(-x));}
__device__ __forceinline__ int   icl(int v,int hi){return min(max(v,0),hi);}
__device__ __forceinline__ u32 h2u(h2 v){return __builtin_bit_cast(u32,v);}
__device__ __forceinline__ h2  u2h(u32 v){return __builtin_bit_cast(h2,v);}
__device__ __forceinline__ float2 up2(u32 v){return __half22float2(u2h(v));}
__device__ __forceinline__ u32 dn2(float a,float b){return h2u(__floats2half2_rn(a,b));}
// packed f16 min/max — no HIP wrapper on ROCm 7.2, emit VOP3P directly
__device__ __forceinline__ u32 pmin2(u32 a,u32 b){u32 d;asm("v_pk_min_f16 %0, %1, %2":"=v"(d):"v"(a),"v"(b));return d;}
__device__ __forceinline__ u32 pmax2(u32 a,u32 b){u32 d;asm("v_pk_max_f16 %0, %1, %2":"=v"(d):"v"(a),"v"(b));return d;}
// shifted pair: (lo = loSrc.hi, hi = hiSrc.lo)
__device__ __forceinline__ u32 shpair(u32 hiSrc,u32 loSrc){return __builtin_amdgcn_alignbit(hiSrc,loSrc,16);}
#define INF2P 0x7C007C00u
#define INF2N 0xFC00FC00u

// MODE 0: init erode — stage f16(input), write e1 = sigmoid(E(x)) (pred vols) / E(y) (true)
// MODE 1: fused first — ghalo=e1, aimg from fp32 input (sigmoided), skel init; write e2
// MODE 2: fused mid   — skel RMW; eaw read pointwise then overwritten with e_{t+2}
// MODE 3: fused last  — skel RMW only, no e write
template<int MODE>
__global__ __launch_bounds__(NT) void step_kernel(const u16* __restrict__ ghalo,
                                                  u16* __restrict__ eaw,
                                                  const float* __restrict__ ypred,
                                                  const float* __restrict__ ytrue,
                                                  u16* __restrict__ skel) {
    const int tx2 = threadIdx.x & 31;
    const int ty  = threadIdx.x >> 5;
    const int x0 = blockIdx.x * TX;
    const int y0 = blockIdx.y * TY;
    const int vol = blockIdx.z / NSLAB;
    const int z0 = (blockIdx.z % NSLAB) * ZS;
    const size_t base = (size_t)vol * DHW;
    const int gxc = x0 + 2*tx2;
    const int gyc = y0 + ty;

    const float* fin = nullptr;
    bool dosig = false;
    if (MODE == 0 || MODE == 1) {
        if (vol < 2) { fin = ypred + base; dosig = true; }
        else         { fin = ytrue + (size_t)(vol-2)*DHW; }
    }

    // packed-f16 raw plane: u32 pair w <-> px (x0-2+2w, x0-2+2w+1), rows gy=y0-1+r
    __shared__ u32 raw[2][TY+2][RPAIRS];

    auto stage = [&](int zi, int buf) {
        if ((unsigned)zi >= DDP) return;
        if (MODE == 0) {
            const float* pl = fin + (size_t)zi * HWP;
            for (int idx = threadIdx.x; idx < (TY+2)*RPAIRS; idx += NT) {
                int r = idx / RPAIRS;
                int w = idx - r*RPAIRS;
                const float* rp = pl + (size_t)icl(y0-1+r, HH-1) * WW;
                int gx0 = x0 - 2 + 2*w;
                float v0, v1;
                if (gx0 < 0)        { v0 = v1 = rp[0]; }
                else if (gx0 >= WW) { v0 = v1 = rp[WW-1]; }
                else { float2 fv = *(const float2*)(rp + gx0); v0 = fv.x; v1 = fv.y; }
                raw[buf][r][w] = dn2(v0, v1);
            }
        } else {
            const u16* pl = ghalo + base + (size_t)zi * HWP;
            for (int idx = threadIdx.x; idx < (TY+2)*RPAIRS; idx += NT) {
                int r = idx / RPAIRS;
                int w = idx - r*RPAIRS;
                const u16* rp = pl + (size_t)icl(y0-1+r, HH-1) * WW;
                int gx0 = x0 - 2 + 2*w;
                u32 v;
                if (gx0 < 0)        { u32 t = rp[0];    v = t | (t<<16); }
                else if (gx0 >= WW) { u32 t = rp[WW-1]; v = t | (t<<16); }
                else v = *(const u32*)(rp + gx0);
                raw[buf][r][w] = v;
            }
        }
    };

    const int w0 = tx2 + 1;        // M pair index (output px pair)
    u32 nr0,nr1,nr2, mr0,mr1,mr2;  // z-rings (packed f16 pairs)
    nr0 = nr1 = nr2 = INF2P;
    mr0 = mr1 = mr2 = INF2N;

    stage(z0-1, (z0-1)&1);
    __syncthreads();

    for (int zi = z0-1; zi <= z0+ZS; ++zi) {
        if (zi < z0+ZS) stage(zi+1, (zi+1)&1);    // issue next plane's loads early

        u32 axn = INF2P;
        u32 axm = INF2N;
        if ((unsigned)zi < DDP) {
            const int b = zi & 1;
            u32 La = raw[b][ty  ][w0-1], Ma = raw[b][ty  ][w0], Ra = raw[b][ty  ][w0+1];
            u32 Lb = raw[b][ty+1][w0-1], Mb = raw[b][ty+1][w0], Rb = raw[b][ty+1][w0+1];
            u32 Lc = raw[b][ty+2][w0-1], Mc = raw[b][ty+2][w0], Rc = raw[b][ty+2][w0+1];
            u32 lsa = shpair(Ma, La), rsa = shpair(Ra, Ma);
            u32 lsb = shpair(Mb, Lb), rsb = shpair(Rb, Mb);
            u32 lsc = shpair(Mc, Lc), rsc = shpair(Rc, Mc);
            u32 na = pmin2(Ma, pmin2(lsa, rsa));
            u32 nb = pmin2(Mb, pmin2(lsb, rsb));
            u32 nc = pmin2(Mc, pmin2(lsc, rsc));
            axn = pmin2(na, pmin2(nb, nc));
            if (MODE != 0) {
                u32 xa = pmax2(Ma, pmax2(lsa, rsa));
                u32 xb = pmax2(Mb, pmax2(lsb, rsb));
                u32 xc = pmax2(Mc, pmax2(lsc, rsc));
                axm = pmax2(xa, pmax2(xb, xc));
            }
        }
        nr0 = nr1; nr1 = nr2; nr2 = axn;
        if (MODE != 0) { mr0 = mr1; mr1 = mr2; mr2 = axm; }

        if (zi >= z0+1) {
            const int zc = zi - 1;
            size_t voff = (size_t)zc*HWP + (size_t)gyc*WW + gxc;
            size_t idx = base + voff;
            u32 e2 = pmin2(nr0, pmin2(nr1, nr2));
            if (MODE == 0) {
                if (dosig) {
                    float2 f = up2(e2);
                    e2 = dn2(sigm(f.x), sigm(f.y));
                }
                *(u32*)(eaw + idx) = e2;
            } else {
                float2 m = up2(pmax2(mr0, pmax2(mr1, mr2)));
                float av0, av1;
                if (MODE == 1) {
                    float2 fv = *(const float2*)(fin + voff);
                    av0 = fv.x; av1 = fv.y;
                    if (dosig) { av0 = sigm(av0); av1 = sigm(av1); }
                } else {
                    float2 a2 = up2(*(const u32*)(eaw + idx));
                    av0 = a2.x; av1 = a2.y;
                }
                float d0 = fmaxf(av0 - m.x, 0.f);
                float d1 = fmaxf(av1 - m.y, 0.f);
                u32 pk;
                if (MODE == 1) {
                    pk = dn2(d0, d1);
                } else {
                    float2 s = up2(*(const u32*)(skel + idx));
                    s.x += fmaxf(d0 - s.x*d0, 0.f);
                    s.y += fmaxf(d1 - s.y*d1, 0.f);
                    pk = dn2(s.x, s.y);
                }
                *(u32*)(skel + idx) = pk;
                if (MODE != 3) *(u32*)(eaw + idx) = e2;
            }
        }
        __syncthreads();
    }
}

// ---------------- deterministic 4-sum reduction (vols 0,1 = pred; 2,3 = true) ----------------
__global__ __launch_bounds__(256) void reduce4_kernel(const u16* __restrict__ skel,
                                                      const float* __restrict__ ytrue,
                                                      const float* __restrict__ ypred,
                                                      float* __restrict__ part) {
    const u32* sp = (const u32*)skel;
    const u32* st = (const u32*)(skel + N2);
    const float2* yt = (const float2*)ytrue;
    const float2* yp = (const float2*)ypred;
    float a0=0.f,a1=0.f,a2=0.f,a3=0.f;
    for (int i = blockIdx.x*256 + threadIdx.x; i < N2/2; i += gridDim.x*256) {
        float2 s = up2(sp[i]);
        float2 u = up2(st[i]);
        float2 t = yt[i]; float2 q = yp[i];
        a0 += s.x*t.x + s.y*t.y;
        a1 += s.x + s.y;
        a2 += u.x*sigm(q.x) + u.y*sigm(q.y);
        a3 += u.x + u.y;
    }
    for (int off=32; off>0; off>>=1) {
        a0+=__shfl_down(a0,off); a1+=__shfl_down(a1,off);
        a2+=__shfl_down(a2,off); a3+=__shfl_down(a3,off);
    }
    __shared__ float red[4][4];
    int wave = threadIdx.x>>6;
    if ((threadIdx.x&63)==0){red[wave][0]=a0;red[wave][1]=a1;red[wave][2]=a2;red[wave][3]=a3;}
    __syncthreads();
    if (threadIdx.x==0){
        float s0=0,s1=0,s2=0,s3=0;
        for(int w=0;w<4;++w){s0+=red[w][0];s1+=red[w][1];s2+=red[w][2];s3+=red[w][3];}
        part[0*RED_BLOCKS+blockIdx.x]=s0; part[1*RED_BLOCKS+blockIdx.x]=s1;
        part[2*RED_BLOCKS+blockIdx.x]=s2; part[3*RED_BLOCKS+blockIdx.x]=s3;
    }
}

__global__ __launch_bounds__(256) void finalize_kernel(const float* __restrict__ part,
                                                       float* __restrict__ out) {
    float a0=0.f,a1=0.f,a2=0.f,a3=0.f;
    for (int i=threadIdx.x;i<RED_BLOCKS;i+=256){
        a0+=part[0*RED_BLOCKS+i]; a1+=part[1*RED_BLOCKS+i];
        a2+=part[2*RED_BLOCKS+i]; a3+=part[3*RED_BLOCKS+i];
    }
    for (int off=32; off>0; off>>=1){
        a0+=__shfl_down(a0,off); a1+=__shfl_down(a1,off);
        a2+=__shfl_down(a2,off); a3+=__shfl_down(a3,off);
    }
    __shared__ float red[4][4];
    int wave = threadIdx.x>>6;
    if ((threadIdx.x&63)==0){red[wave][0]=a0;red[wave][1]=a1;red[wave][2]=a2;red[wave][3]=a3;}
    __syncthreads();
    if (threadIdx.x==0){
        float s0=0,s1=0,s2=0,s3=0;
        for(int w=0;w<4;++w){s0+=red[w][0];s1+=red[w][1];s2+=red[w][2];s3+=red[w][3];}
        float tprec=(s0+1.f)/(s1+1.f);
        float tsens=(s2+1.f)/(s3+1.f);
        float cl2=2.f*tprec*tsens/(tprec+tsens+1.f);
        out[0]=1.f-cl2;
    }
}

__global__ void sentinel_kernel(float* out, float v){ out[0]=v; }

extern "C" void kernel_launch(void* const* d_in, const int* in_sizes, int n_in,
                              void* d_out, int out_size, void* d_ws, size_t ws_size,
                              hipStream_t stream) {
    const float* ypred = (const float*)d_in[0];
    const float* ytrue = (const float*)d_in[1];
    float* out = (float*)d_out;

    const size_t need = (size_t)3*N4*sizeof(u16) + (size_t)4*RED_BLOCKS*sizeof(float);
    if (ws_size < need) { sentinel_kernel<<<1,1,0,stream>>>(out,-111111.f); return; }

    u16* EA   = (u16*)d_ws;
    u16* EB   = EA + N4;
    u16* SKEL = EB + N4;
    float* PART = (float*)(SKEL + N4);

    dim3 grid(WW/TX, HH/TY, 4*NSLAB);   // 4 x 32 x 32 = 4096 blocks

    // EB = e_1 = E(f(x))   (sigmoid fused at write for pred vols)
    step_kernel<0><<<grid, NT, 0, stream>>>(nullptr, EB, ypred, ytrue, nullptr);
    // skel = relu(e_0 - M(e_1));  EA <- e_2 = E(e_1)
    step_kernel<1><<<grid, NT, 0, stream>>>(EB, EA, ypred, ytrue, SKEL);

    u16* h = EA;   // e_{t+1}
    u16* a = EB;   // e_t  (overwritten with e_{t+2})
    for (int t = 1; t <= NITER; ++t) {
        if (t < NITER) step_kernel<2><<<grid, NT, 0, stream>>>(h, a, nullptr, nullptr, SKEL);
        else           step_kernel<3><<<grid, NT, 0, stream>>>(h, a, nullptr, nullptr, SKEL);
        u16* tmp = h; h = a; a = tmp;
    }

    reduce4_kernel<<<RED_BLOCKS, 256, 0, stream>>>(SKEL, ytrue, ypred, PART);
    finalize_kernel<<<1, 256, 0, stream>>>(PART, out);
}